// Round 1
// baseline (321.555 us; speedup 1.0000x reference)
//
#include <hip/hip_runtime.h>

typedef unsigned short u16;
typedef __attribute__((ext_vector_type(8))) short bf16x8;
typedef __attribute__((ext_vector_type(4))) float f32x4;

#define TP 28
#define NB 4096

__device__ __forceinline__ u16 f2bf(float x) {
  union { float f; unsigned u; } v; v.f = x;
  unsigned u = v.u;
  return (u16)((u + 0x7fffu + ((u >> 16) & 1u)) >> 16);
}
__device__ __forceinline__ float sigm(float x) { return 1.0f / (1.0f + __expf(-x)); }
__device__ __forceinline__ float tanh_(float x) { return 1.0f - 2.0f / (1.0f + __expf(2.0f * x)); }
__device__ __forceinline__ float leaky(float x) { return x >= 0.0f ? x : 0.1f * x; }
__device__ __forceinline__ f32x4 mfma16(bf16x8 a, bf16x8 b, f32x4 c) {
  return __builtin_amdgcn_mfma_f32_16x16x32_bf16(a, b, c, 0, 0, 0);
}
__device__ __forceinline__ bf16x8 ldfrag8(const float* p) {
  float4 u0 = *(const float4*)p;
  float4 u1 = *(const float4*)(p + 4);
  bf16x8 f;
  f[0] = (short)f2bf(u0.x); f[1] = (short)f2bf(u0.y);
  f[2] = (short)f2bf(u0.z); f[3] = (short)f2bf(u0.w);
  f[4] = (short)f2bf(u1.x); f[5] = (short)f2bf(u1.y);
  f[6] = (short)f2bf(u1.z); f[7] = (short)f2bf(u1.w);
  return f;
}

// ---------------- conv1: [B,34,180] -> y1 [B,16,32] + BN1 partials ----------------
__global__ __launch_bounds__(256) void k_conv1(
    const float* __restrict__ poses, const float* __restrict__ w1,
    const float* __restrict__ b1, float* __restrict__ y1,
    float* __restrict__ p1)
{
  __shared__ __align__(16) float xls[4][180][36];
  __shared__ __align__(16) float wls[540 * 16];
  __shared__ float sp[4][16][2];
  const int tid = threadIdx.x;
  const int blk = blockIdx.x;
  // w1[co][ci][k] -> wls[(ci*3+k)*16+co]
  for (int i = tid; i < 8640; i += 256) {
    int co = i / 540, r = i % 540;
    wls[r * 16 + co] = w1[i];
  }
  for (int i = tid; i < 4 * 6120; i += 256) {
    int wb = i / 6120, rem = i % 6120;
    int tt = rem / 180, ci = rem % 180;
    xls[wb][ci][tt] = poses[((size_t)(blk * 4 + wb) * 34 + tt) * 180 + ci];
  }
  __syncthreads();
  const int lane = tid & 63, w = tid >> 6;
  const int cg = lane >> 3, tg = lane & 7;
  const int t0 = tg * 4;
  const int co0 = cg * 2;
  float acc0[4] = {0, 0, 0, 0}, acc1[4] = {0, 0, 0, 0};
  for (int ci = 0; ci < 180; ++ci) {
    const float* xr = &xls[w][ci][0];
    float4 xa = *(const float4*)(xr + t0);
    float2 xb = *(const float2*)(xr + t0 + 4);
    float xv[6] = {xa.x, xa.y, xa.z, xa.w, xb.x, xb.y};
#pragma unroll
    for (int k = 0; k < 3; ++k) {
      float2 wvv = *(const float2*)&wls[(3 * ci + k) * 16 + co0];
#pragma unroll
      for (int j = 0; j < 4; ++j) {
        acc0[j] += xv[j + k] * wvv.x;
        acc1[j] += xv[j + k] * wvv.y;
      }
    }
  }
  const float bc0 = b1[co0], bc1 = b1[co0 + 1];
  const int b = blk * 4 + w;
  float s0 = 0, q0 = 0, s1 = 0, q1 = 0;
  float o0[4], o1[4];
#pragma unroll
  for (int j = 0; j < 4; ++j) {
    o0[j] = acc0[j] + bc0; o1[j] = acc1[j] + bc1;
    s0 += o0[j]; q0 += o0[j] * o0[j];
    s1 += o1[j]; q1 += o1[j] * o1[j];
  }
  *(float4*)&y1[(size_t)b * 512 + co0 * 32 + t0] = make_float4(o0[0], o0[1], o0[2], o0[3]);
  *(float4*)&y1[(size_t)b * 512 + (co0 + 1) * 32 + t0] = make_float4(o1[0], o1[1], o1[2], o1[3]);
#pragma unroll
  for (int m = 1; m <= 4; m <<= 1) {
    s0 += __shfl_xor(s0, m); q0 += __shfl_xor(q0, m);
    s1 += __shfl_xor(s1, m); q1 += __shfl_xor(q1, m);
  }
  if (tg == 0) {
    sp[w][co0][0] = s0; sp[w][co0][1] = q0;
    sp[w][co0 + 1][0] = s1; sp[w][co0 + 1][1] = q1;
  }
  __syncthreads();
  if (tid < 32) {
    int s = tid >> 4, c = tid & 15;
    p1[blk * 32 + s * 16 + c] = sp[0][c][s] + sp[1][c][s] + sp[2][c][s] + sp[3][c][s];
  }
}

__global__ __launch_bounds__(256) void k_stats1(
    const float* __restrict__ p1, const float* __restrict__ g,
    const float* __restrict__ bb, float* __restrict__ sc)
{
  __shared__ float red[8][32];
  __shared__ float tot[32];
  const int tid = threadIdx.x;
  const int col = tid & 31, r0 = tid >> 5;
  float a = 0;
  for (int r = r0; r < 1024; r += 8) a += p1[r * 32 + col];
  red[r0][col] = a;
  __syncthreads();
  if (tid < 32) {
    float t = 0;
    for (int i = 0; i < 8; ++i) t += red[i][tid];
    tot[tid] = t;
  }
  __syncthreads();
  if (tid < 16) {
    const float inv = 1.0f / 131072.0f;
    float m = tot[tid] * inv;
    float var = tot[16 + tid] * inv - m * m;
    float s = g[tid] * rsqrtf(var + 1e-5f);
    sc[tid] = s;
    sc[16 + tid] = bb[tid] - m * s;
  }
}

// -------- conv2: bn1+leaky(y1) -> y2 [B,8,30] + BN2 partials --------
__global__ __launch_bounds__(256) void k_conv2(
    const float* __restrict__ y1, const float* __restrict__ sc,
    const float* __restrict__ w2, const float* __restrict__ b2,
    float* __restrict__ y2, float* __restrict__ p2)
{
  __shared__ float a1[8][16][33];
  __shared__ float w2s[384];
  __shared__ float sp[4][8][2];
  const int tid = threadIdx.x;
  const int b0 = blockIdx.x * 8;
  for (int i = tid; i < 384; i += 256) w2s[i] = w2[i];
  for (int i = tid; i < 4096; i += 256) {
    int bb = i >> 9, c = (i >> 5) & 15, t = i & 31;
    float v = y1[(size_t)(b0 + bb) * 512 + c * 32 + t] * sc[c] + sc[16 + c];
    a1[bb][c][t] = leaky(v);
  }
  __syncthreads();
  float acc[8];
  const int bb = tid / 30, t = tid % 30;
  const bool act = tid < 240;
#pragma unroll
  for (int co = 0; co < 8; ++co) acc[co] = act ? b2[co] : 0.0f;
  if (act) {
    for (int ci = 0; ci < 16; ++ci) {
      float x0 = a1[bb][ci][t], x1 = a1[bb][ci][t + 1], x2 = a1[bb][ci][t + 2];
#pragma unroll
      for (int co = 0; co < 8; ++co) {
        const float* wp = &w2s[co * 48 + ci * 3];
        acc[co] += x0 * wp[0] + x1 * wp[1] + x2 * wp[2];
      }
    }
    for (int co = 0; co < 8; ++co)
      y2[(size_t)(b0 + bb) * 240 + co * 30 + t] = acc[co];
  }
  const int w = tid >> 6;
#pragma unroll
  for (int co = 0; co < 8; ++co) {
    float s = act ? acc[co] : 0.0f;
    float q = s * s;
#pragma unroll
    for (int m = 1; m <= 32; m <<= 1) { s += __shfl_xor(s, m); q += __shfl_xor(q, m); }
    if ((tid & 63) == 0) { sp[w][co][0] = s; sp[w][co][1] = q; }
  }
  __syncthreads();
  if (tid < 16) {
    int s = tid >> 3, c = tid & 7;
    p2[blockIdx.x * 16 + s * 8 + c] = sp[0][c][s] + sp[1][c][s] + sp[2][c][s] + sp[3][c][s];
  }
}

__global__ __launch_bounds__(256) void k_stats2(
    const float* __restrict__ p2, const float* __restrict__ g,
    const float* __restrict__ bb, float* __restrict__ sc)
{
  __shared__ float red[16][16];
  __shared__ float tot[16];
  const int tid = threadIdx.x;
  const int col = tid & 15, r0 = tid >> 4;
  float a = 0;
  for (int r = r0; r < 512; r += 16) a += p2[r * 16 + col];
  red[r0][col] = a;
  __syncthreads();
  if (tid < 16) {
    float t = 0;
    for (int i = 0; i < 16; ++i) t += red[i][tid];
    tot[tid] = t;
  }
  __syncthreads();
  if (tid < 8) {
    const float inv = 1.0f / 122880.0f;
    float m = tot[tid] * inv;
    float var = tot[8 + tid] * inv - m * m;
    float s = g[tid] * rsqrtf(var + 1e-5f);
    sc[32 + tid] = s;
    sc[40 + tid] = bb[tid] - m * s;
  }
}

// -------- conv3: bn2+leaky(y2) -> feat [28][B][8] (time-major) --------
__global__ __launch_bounds__(256) void k_conv3(
    const float* __restrict__ y2, const float* __restrict__ sc,
    const float* __restrict__ w3, const float* __restrict__ b3,
    float* __restrict__ feat)
{
  __shared__ float a2[8][8][31];
  __shared__ float w3s[192];
  const int tid = threadIdx.x;
  const int b0 = blockIdx.x * 8;
  for (int i = tid; i < 192; i += 256) w3s[i] = w3[i];
  for (int i = tid; i < 1920; i += 256) {
    int bb = i / 240, rem = i % 240, c = rem / 30, t = rem % 30;
    float v = y2[(size_t)(b0 + bb) * 240 + c * 30 + t] * sc[32 + c] + sc[40 + c];
    a2[bb][c][t] = leaky(v);
  }
  __syncthreads();
  if (tid < 224) {
    int bb = tid / 28, t = tid % 28;
    float acc[8];
#pragma unroll
    for (int co = 0; co < 8; ++co) acc[co] = b3[co];
    for (int ci = 0; ci < 8; ++ci) {
      float x0 = a2[bb][ci][t], x1 = a2[bb][ci][t + 1], x2 = a2[bb][ci][t + 2];
#pragma unroll
      for (int co = 0; co < 8; ++co) {
        const float* wp = &w3s[co * 24 + ci * 3];
        acc[co] += x0 * wp[0] + x1 * wp[1] + x2 * wp[2];
      }
    }
    float* fp = &feat[((size_t)t * NB + b0 + bb) * 8];
    *(float4*)fp = make_float4(acc[0], acc[1], acc[2], acc[3]);
    *(float4*)(fp + 4) = make_float4(acc[4], acc[5], acc[6], acc[7]);
  }
}

// -------- GRU layer: xin [28][B][DIN] -> xout [28][B][64], MFMA bf16 --------
template <int DIN>
__global__ __launch_bounds__(256) void k_gru(
    const float* __restrict__ xin, float* __restrict__ xout,
    const float* __restrict__ wih, const float* __restrict__ whh,
    const float* __restrict__ bih, const float* __restrict__ bhh)
{
  constexpr int XP = (DIN == 64) ? 72 : 40;
  __shared__ __align__(16) u16 xl[16][XP];
  __shared__ __align__(16) u16 hl[16][72];
  const int tid = threadIdx.x;
  const int b0 = blockIdx.x * 16;
  const int lane = tid & 63;
  const int wv = tid >> 6;
  const int row = lane & 15;
  const int kg = (lane >> 4) * 8;
  const int R0 = (lane >> 4) * 4;
  const int cr = 16 * wv + row;

  for (int i = tid; i < 16 * 72; i += 256) hl[i / 72][i % 72] = 0;
  if (DIN == 8) {
    for (int i = tid; i < 16 * XP; i += 256) xl[i / XP][i % XP] = 0;
  }

  // weight B-fragments held in registers for the whole t-loop
  bf16x8 Wx[3][2], Wh[3][2];
#pragma unroll
  for (int g = 0; g < 3; ++g) {
    const int n = g * 64 + cr;
#pragma unroll
    for (int s = 0; s < 2; ++s) Wh[g][s] = ldfrag8(whh + n * 64 + s * 32 + kg);
    if (DIN == 64) {
#pragma unroll
      for (int s = 0; s < 2; ++s) Wx[g][s] = ldfrag8(wih + n * 64 + s * 32 + kg);
    } else {
      bf16x8 z;
#pragma unroll
      for (int j = 0; j < 8; ++j) z[j] = 0;
      if (kg == 0) z = ldfrag8(wih + n * 8);
      Wx[g][0] = z;
      Wx[g][1] = z;
    }
  }

  const float b_r = bih[cr] + bhh[cr];
  const float b_z = bih[64 + cr] + bhh[64 + cr];
  const float b_i = bih[128 + cr];
  const float b_h = bhh[128 + cr];
  float hold[4] = {0.f, 0.f, 0.f, 0.f};

  float2 pf0 = make_float2(0.f, 0.f), pf1 = make_float2(0.f, 0.f);
  auto loadX = [&](int tt) {
    if (DIN == 64) {
      const float* src = xin + ((size_t)tt * NB + b0) * 64;
      const int p0 = tid * 2;
      pf0 = *(const float2*)(src + (p0 >> 5) * 64 + ((p0 & 31) << 1));
      pf1 = *(const float2*)(src + ((p0 + 1) >> 5) * 64 + (((p0 + 1) & 31) << 1));
    } else {
      if (tid < 64) {
        const float* src = xin + ((size_t)tt * NB + b0) * 8;
        pf0 = *(const float2*)(src + (tid >> 2) * 8 + ((tid & 3) << 1));
      }
    }
  };
  auto commitX = [&]() {
    if (DIN == 64) {
      const int p0 = tid * 2;
      unsigned a = (unsigned)f2bf(pf0.x) | ((unsigned)f2bf(pf0.y) << 16);
      unsigned b = (unsigned)f2bf(pf1.x) | ((unsigned)f2bf(pf1.y) << 16);
      *(unsigned*)&xl[p0 >> 5][(p0 & 31) << 1] = a;
      *(unsigned*)&xl[(p0 + 1) >> 5][((p0 + 1) & 31) << 1] = b;
    } else {
      if (tid < 64) {
        unsigned a = (unsigned)f2bf(pf0.x) | ((unsigned)f2bf(pf0.y) << 16);
        *(unsigned*)&xl[tid >> 2][(tid & 3) << 1] = a;
      }
    }
  };

  loadX(0);
  __syncthreads();
  commitX();
  __syncthreads();

  for (int t = 0; t < TP; ++t) {
    if (t + 1 < TP) loadX(t + 1);

    bf16x8 ax0 = *(const bf16x8*)&xl[row][kg];
    bf16x8 ah0 = *(const bf16x8*)&hl[row][kg];
    bf16x8 ah1 = *(const bf16x8*)&hl[row][32 + kg];

    f32x4 ar = {b_r, b_r, b_r, b_r};
    f32x4 az = {b_z, b_z, b_z, b_z};
    f32x4 ai = {b_i, b_i, b_i, b_i};
    f32x4 an = {b_h, b_h, b_h, b_h};

    ar = mfma16(ax0, Wx[0][0], ar);
    az = mfma16(ax0, Wx[1][0], az);
    ai = mfma16(ax0, Wx[2][0], ai);
    if (DIN == 64) {
      bf16x8 ax1 = *(const bf16x8*)&xl[row][32 + kg];
      ar = mfma16(ax1, Wx[0][1], ar);
      az = mfma16(ax1, Wx[1][1], az);
      ai = mfma16(ax1, Wx[2][1], ai);
    }
    ar = mfma16(ah0, Wh[0][0], ar);
    ar = mfma16(ah1, Wh[0][1], ar);
    az = mfma16(ah0, Wh[1][0], az);
    az = mfma16(ah1, Wh[1][1], az);
    an = mfma16(ah0, Wh[2][0], an);
    an = mfma16(ah1, Wh[2][1], an);

    float hnew[4];
#pragma unroll
    for (int r = 0; r < 4; ++r) {
      float rr = sigm(ar[r]);
      float zz = sigm(az[r]);
      float nn = tanh_(ai[r] + rr * an[r]);
      hnew[r] = nn + zz * (hold[r] - nn);
      hold[r] = hnew[r];
    }
    {
      float* dst = xout + ((size_t)t * NB + b0 + R0) * 64 + cr;
      dst[0] = hnew[0];
      dst[64] = hnew[1];
      dst[128] = hnew[2];
      dst[192] = hnew[3];
    }
    __syncthreads();
#pragma unroll
    for (int r = 0; r < 4; ++r) hl[R0 + r][cr] = f2bf(hnew[r]);
    if (t + 1 < TP) commitX();
    __syncthreads();
  }
}

// -------- head: [28][B][64] -> sigmoid(B) --------
__global__ __launch_bounds__(256) void k_head(
    const float* __restrict__ hseq, const float* __restrict__ ow,
    const float* __restrict__ ob, const float* __restrict__ o2w,
    const float* __restrict__ o2b, float* __restrict__ out)
{
  const int tid = threadIdx.x, lane = tid & 63, w = tid >> 6;
  const int b = blockIdx.x * 4 + w;
  const float wv = ow[lane];
  const float obv = ob[0];
  float acc = 0.f;
  for (int t = 0; t < TP; ++t) {
    float v = hseq[((size_t)t * NB + b) * 64 + lane] * wv;
#pragma unroll
    for (int m = 1; m <= 32; m <<= 1) v += __shfl_xor(v, m);
    acc += (v + obv) * o2w[t];
  }
  if (lane == 0) out[b] = sigm(acc + o2b[0]);
}

extern "C" void kernel_launch(void* const* d_in, const int* in_sizes, int n_in,
                              void* d_out, int out_size, void* d_ws, size_t ws_size,
                              hipStream_t stream)
{
  const float* poses = (const float*)d_in[0];
  const float* c1w = (const float*)d_in[1];
  const float* c1b = (const float*)d_in[2];
  const float* bn1g = (const float*)d_in[3];
  const float* bn1b = (const float*)d_in[4];
  const float* c2w = (const float*)d_in[5];
  const float* c2b = (const float*)d_in[6];
  const float* bn2g = (const float*)d_in[7];
  const float* bn2b = (const float*)d_in[8];
  const float* c3w = (const float*)d_in[9];
  const float* c3b = (const float*)d_in[10];
  const float* g0wih = (const float*)d_in[11];  // [192][8]
  const float* gwih = (const float*)d_in[12];   // [3][192][64]
  const float* gwhh = (const float*)d_in[13];   // [4][192][64]
  const float* gbih = (const float*)d_in[14];   // [4][192]
  const float* gbhh = (const float*)d_in[15];   // [4][192]
  const float* ow = (const float*)d_in[16];
  const float* ob = (const float*)d_in[17];
  const float* o2w = (const float*)d_in[18];
  const float* o2b = (const float*)d_in[19];

  float* ws = (float*)d_ws;
  float* y1 = ws;                    // 2097152
  float* y2 = ws + 2097152;          // 983040
  float* feat = ws + 3080192;        // 917504
  float* bufA = ws + 3997696;        // 7340032
  float* bufB = ws + 11337728;       // 7340032
  float* p1 = ws + 18677760;         // 32768
  float* p2 = ws + 18710528;         // 8192
  float* sc = ws + 18718720;         // 48
  float* outv = (float*)d_out;

  k_conv1<<<dim3(1024), dim3(256), 0, stream>>>(poses, c1w, c1b, y1, p1);
  k_stats1<<<dim3(1), dim3(256), 0, stream>>>(p1, bn1g, bn1b, sc);
  k_conv2<<<dim3(512), dim3(256), 0, stream>>>(y1, sc, c2w, c2b, y2, p2);
  k_stats2<<<dim3(1), dim3(256), 0, stream>>>(p2, bn2g, bn2b, sc);
  k_conv3<<<dim3(512), dim3(256), 0, stream>>>(y2, sc, c3w, c3b, feat);
  k_gru<8><<<dim3(256), dim3(256), 0, stream>>>(feat, bufA, g0wih, gwhh + 0 * 12288, gbih + 0, gbhh + 0);
  k_gru<64><<<dim3(256), dim3(256), 0, stream>>>(bufA, bufB, gwih + 0 * 12288, gwhh + 1 * 12288, gbih + 192, gbhh + 192);
  k_gru<64><<<dim3(256), dim3(256), 0, stream>>>(bufB, bufA, gwih + 1 * 12288, gwhh + 2 * 12288, gbih + 384, gbhh + 384);
  k_gru<64><<<dim3(256), dim3(256), 0, stream>>>(bufA, bufB, gwih + 2 * 12288, gwhh + 3 * 12288, gbih + 576, gbhh + 576);
  k_head<<<dim3(1024), dim3(256), 0, stream>>>(bufB, ow, ob, o2w, o2b, outv);
}

// Round 4
// 214.021 us; speedup vs baseline: 1.5024x; 1.5024x over previous
//
#include <hip/hip_runtime.h>

typedef unsigned short u16;
typedef __attribute__((ext_vector_type(8))) short bf16x8;
typedef __attribute__((ext_vector_type(4))) float f32x4;

#define TP 28
#define NB 4096

__device__ __forceinline__ u16 f2bf(float x) {
  union { float f; unsigned u; } v; v.f = x;
  unsigned u = v.u;
  return (u16)((u + 0x7fffu + ((u >> 16) & 1u)) >> 16);
}
__device__ __forceinline__ float bf2f(u16 h) {
  union { unsigned u; float f; } v; v.u = ((unsigned)h) << 16; return v.f;
}
__device__ __forceinline__ float sigm(float x) { return 1.0f / (1.0f + __expf(-x)); }
__device__ __forceinline__ float tanh_(float x) { return 1.0f - 2.0f / (1.0f + __expf(2.0f * x)); }
__device__ __forceinline__ float leaky(float x) { return x >= 0.0f ? x : 0.1f * x; }
__device__ __forceinline__ f32x4 mfma16(bf16x8 a, bf16x8 b, f32x4 c) {
  return __builtin_amdgcn_mfma_f32_16x16x32_bf16(a, b, c, 0, 0, 0);
}
__device__ __forceinline__ bf16x8 pack8(float4 a, float4 b) {
  bf16x8 f;
  f[0] = (short)f2bf(a.x); f[1] = (short)f2bf(a.y);
  f[2] = (short)f2bf(a.z); f[3] = (short)f2bf(a.w);
  f[4] = (short)f2bf(b.x); f[5] = (short)f2bf(b.y);
  f[6] = (short)f2bf(b.z); f[7] = (short)f2bf(b.w);
  return f;
}
__device__ __forceinline__ bf16x8 ldfrag8(const float* p) {
  float4 u0 = *(const float4*)p;
  float4 u1 = *(const float4*)(p + 4);
  return pack8(u0, u1);
}

// ---------------- conv1 as MFMA GEMM: patches[32B x 540] x W[540 x 16] ----------------
// A read direct from global (contiguous patches, L1-served), W transposed into LDS bf16.
__global__ __launch_bounds__(256, 4) void k_conv1(
    const float* __restrict__ poses, const float* __restrict__ w1,
    const float* __restrict__ b1, float* __restrict__ y1,
    float* __restrict__ p1)
{
  __shared__ __align__(16) u16 wt[16][544];  // [co][k], k = tap*180+ci, padded w/ zeros
  __shared__ float sp[4][16][2];
  const int tid = threadIdx.x;
  for (int i = tid; i < 16 * 544; i += 256) ((u16*)wt)[i] = 0;
  __syncthreads();
  for (int i = tid; i < 8640; i += 256) {
    int co = i / 540, r = i % 540, ci = r / 3, tap = r % 3;
    wt[co][tap * 180 + ci] = f2bf(w1[i]);
  }
  __syncthreads();

  const int lane = tid & 63;
  const int wv = tid >> 6;
  const int row = lane & 15;   // A-row (t pos) and B-col (co)
  const int kgrp = lane >> 4;
  const int kg = kgrp * 8;
  const int b = blockIdx.x * 4 + wv;
  const float* xb = poses + (size_t)b * 6120;
  const float* r0 = xb + row * 180;          // patch for t = row      (contiguous 540)
  const float* r1 = xb + (16 + row) * 180;   // patch for t = 16 + row

  const float bias = b1[row];
  f32x4 acc0 = {bias, bias, bias, bias};
  f32x4 acc1 = acc0;

#pragma unroll 4
  for (int s = 0; s < 16; ++s) {
    bf16x8 wf = *(const bf16x8*)&wt[row][s * 32 + kg];
    const float* pa = r0 + s * 32 + kg;
    const float* pb = r1 + s * 32 + kg;
    bf16x8 a0 = pack8(*(const float4*)pa, *(const float4*)(pa + 4));
    bf16x8 a1 = pack8(*(const float4*)pb, *(const float4*)(pb + 4));
    acc0 = mfma16(a0, wf, acc0);
    acc1 = mfma16(a1, wf, acc1);
  }
  { // tail slice: k 512..543, weights 540..543 are zero-padded; clamp A addr for kg=24
    const int c0 = 512 + kg;
    const int c1 = c0 + ((kg < 24) ? 4 : 0);
    bf16x8 wf = *(const bf16x8*)&wt[row][c0];
    bf16x8 a0 = pack8(*(const float4*)(r0 + c0), *(const float4*)(r0 + c1));
    bf16x8 a1 = pack8(*(const float4*)(r1 + c0), *(const float4*)(r1 + c1));
    acc0 = mfma16(a0, wf, acc0);
    acc1 = mfma16(a1, wf, acc1);
  }

  // epilogue: store y1 [B][16][32] + BN partials
  float s_ = 0.f, q_ = 0.f;
  float* yb = y1 + (size_t)b * 512 + row * 32 + kgrp * 4;
#pragma unroll
  for (int r = 0; r < 4; ++r) {
    float v0 = acc0[r], v1 = acc1[r];
    yb[r] = v0;
    yb[16 + r] = v1;
    s_ += v0 + v1;
    q_ += v0 * v0 + v1 * v1;
  }
  s_ += __shfl_xor(s_, 16); q_ += __shfl_xor(q_, 16);
  s_ += __shfl_xor(s_, 32); q_ += __shfl_xor(q_, 32);
  if (lane < 16) { sp[wv][lane][0] = s_; sp[wv][lane][1] = q_; }
  __syncthreads();
  if (tid < 32) {
    int ss = tid >> 4, c = tid & 15;
    p1[blockIdx.x * 32 + ss * 16 + c] = sp[0][c][ss] + sp[1][c][ss] + sp[2][c][ss] + sp[3][c][ss];
  }
}

__global__ __launch_bounds__(256) void k_stats1(
    const float* __restrict__ p1, const float* __restrict__ g,
    const float* __restrict__ bb, float* __restrict__ sc)
{
  __shared__ float red[8][32];
  __shared__ float tot[32];
  const int tid = threadIdx.x;
  const int col = tid & 31, r0 = tid >> 5;
  float a = 0;
  for (int r = r0; r < 1024; r += 8) a += p1[r * 32 + col];
  red[r0][col] = a;
  __syncthreads();
  if (tid < 32) {
    float t = 0;
    for (int i = 0; i < 8; ++i) t += red[i][tid];
    tot[tid] = t;
  }
  __syncthreads();
  if (tid < 16) {
    const float inv = 1.0f / 131072.0f;
    float m = tot[tid] * inv;
    float var = tot[16 + tid] * inv - m * m;
    float s = g[tid] * rsqrtf(fmaxf(var, 0.0f) + 1e-5f);
    sc[tid] = s;
    sc[16 + tid] = bb[tid] - m * s;
  }
}

// -------- conv2: bn1+leaky(y1) -> y2 [B,8,30] + BN2 partials --------
__global__ __launch_bounds__(256) void k_conv2(
    const float* __restrict__ y1, const float* __restrict__ sc,
    const float* __restrict__ w2, const float* __restrict__ b2,
    float* __restrict__ y2, float* __restrict__ p2)
{
  __shared__ float a1[8][16][33];
  __shared__ float w2s[384];
  __shared__ float sp[4][8][2];
  const int tid = threadIdx.x;
  const int b0 = blockIdx.x * 8;
  for (int i = tid; i < 384; i += 256) w2s[i] = w2[i];
  for (int i = tid; i < 4096; i += 256) {
    int bb = i >> 9, c = (i >> 5) & 15, t = i & 31;
    float v = y1[(size_t)(b0 + bb) * 512 + c * 32 + t] * sc[c] + sc[16 + c];
    a1[bb][c][t] = leaky(v);
  }
  __syncthreads();
  float acc[8];
  const int bb = tid / 30, t = tid % 30;
  const bool act = tid < 240;
#pragma unroll
  for (int co = 0; co < 8; ++co) acc[co] = act ? b2[co] : 0.0f;
  if (act) {
    for (int ci = 0; ci < 16; ++ci) {
      float x0 = a1[bb][ci][t], x1 = a1[bb][ci][t + 1], x2 = a1[bb][ci][t + 2];
#pragma unroll
      for (int co = 0; co < 8; ++co) {
        const float* wp = &w2s[co * 48 + ci * 3];
        acc[co] += x0 * wp[0] + x1 * wp[1] + x2 * wp[2];
      }
    }
    for (int co = 0; co < 8; ++co)
      y2[(size_t)(b0 + bb) * 240 + co * 30 + t] = acc[co];
  }
  const int w = tid >> 6;
#pragma unroll
  for (int co = 0; co < 8; ++co) {
    float s = act ? acc[co] : 0.0f;
    float q = s * s;
#pragma unroll
    for (int m = 1; m <= 32; m <<= 1) { s += __shfl_xor(s, m); q += __shfl_xor(q, m); }
    if ((tid & 63) == 0) { sp[w][co][0] = s; sp[w][co][1] = q; }
  }
  __syncthreads();
  if (tid < 16) {
    int s = tid >> 3, c = tid & 7;
    p2[blockIdx.x * 16 + s * 8 + c] = sp[0][c][s] + sp[1][c][s] + sp[2][c][s] + sp[3][c][s];
  }
}

__global__ __launch_bounds__(256) void k_stats2(
    const float* __restrict__ p2, const float* __restrict__ g,
    const float* __restrict__ bb, float* __restrict__ sc)
{
  __shared__ float red[16][16];
  __shared__ float tot[16];
  const int tid = threadIdx.x;
  const int col = tid & 15, r0 = tid >> 4;
  float a = 0;
  for (int r = r0; r < 512; r += 16) a += p2[r * 16 + col];
  red[r0][col] = a;
  __syncthreads();
  if (tid < 16) {
    float t = 0;
    for (int i = 0; i < 16; ++i) t += red[i][tid];
    tot[tid] = t;
  }
  __syncthreads();
  if (tid < 8) {
    const float inv = 1.0f / 122880.0f;
    float m = tot[tid] * inv;
    float var = tot[8 + tid] * inv - m * m;
    float s = g[tid] * rsqrtf(fmaxf(var, 0.0f) + 1e-5f);
    sc[32 + tid] = s;
    sc[40 + tid] = bb[tid] - m * s;
  }
}

// -------- conv3: bn2+leaky(y2) -> feat [28][B][8] bf16 (time-major) --------
__global__ __launch_bounds__(256) void k_conv3(
    const float* __restrict__ y2, const float* __restrict__ sc,
    const float* __restrict__ w3, const float* __restrict__ b3,
    u16* __restrict__ feat)
{
  __shared__ float a2[8][8][31];
  __shared__ float w3s[192];
  const int tid = threadIdx.x;
  const int b0 = blockIdx.x * 8;
  for (int i = tid; i < 192; i += 256) w3s[i] = w3[i];
  for (int i = tid; i < 1920; i += 256) {
    int bb = i / 240, rem = i % 240, c = rem / 30, t = rem % 30;
    float v = y2[(size_t)(b0 + bb) * 240 + c * 30 + t] * sc[32 + c] + sc[40 + c];
    a2[bb][c][t] = leaky(v);
  }
  __syncthreads();
  if (tid < 224) {
    int bb = tid / 28, t = tid % 28;
    float acc[8];
#pragma unroll
    for (int co = 0; co < 8; ++co) acc[co] = b3[co];
    for (int ci = 0; ci < 8; ++ci) {
      float x0 = a2[bb][ci][t], x1 = a2[bb][ci][t + 1], x2 = a2[bb][ci][t + 2];
#pragma unroll
      for (int co = 0; co < 8; ++co) {
        const float* wp = &w3s[co * 24 + ci * 3];
        acc[co] += x0 * wp[0] + x1 * wp[1] + x2 * wp[2];
      }
    }
    union { u16 h[8]; uint4 v; } u;
#pragma unroll
    for (int co = 0; co < 8; ++co) u.h[co] = f2bf(acc[co]);
    *(uint4*)&feat[((size_t)t * NB + b0 + bb) * 8] = u.v;
  }
}

// -------- GRU layer: xin [28][B][DIN] bf16 -> xout [28][B][64] bf16 --------
// 16 batches/block (grid 256, full ownership, no shadow rows).
// Double-buffered LDS, one barrier per timestep.
template <int DIN>
__global__ __launch_bounds__(256) void k_gru(
    const u16* __restrict__ xin, u16* __restrict__ xout,
    const float* __restrict__ wih, const float* __restrict__ whh,
    const float* __restrict__ bih, const float* __restrict__ bhh)
{
  constexpr int XP = (DIN == 64) ? 72 : 40;
  __shared__ __align__(16) u16 xl[2][16][XP];
  __shared__ __align__(16) u16 hl[2][16][72];
  const int tid = threadIdx.x;
  const int b0 = blockIdx.x * 16;
  const int lane = tid & 63;
  const int wv = tid >> 6;
  const int row = lane & 15;
  const int kgrp = lane >> 4;
  const int kg = kgrp * 8;
  const int R0 = kgrp * 4;
  const int cr = 16 * wv + row;

  for (int i = tid; i < 16 * 72; i += 256) hl[0][i / 72][i % 72] = 0;
  if (DIN == 8) {
    for (int i = tid; i < 2 * 16 * XP; i += 256) ((u16*)xl)[i] = 0;
  }

  // weight B-fragments in registers for the whole t-loop
  bf16x8 Wx[3][2], Wh[3][2];
#pragma unroll
  for (int g = 0; g < 3; ++g) {
    const int n = g * 64 + cr;
#pragma unroll
    for (int s = 0; s < 2; ++s) Wh[g][s] = ldfrag8(whh + n * 64 + s * 32 + kg);
    if (DIN == 64) {
#pragma unroll
      for (int s = 0; s < 2; ++s) Wx[g][s] = ldfrag8(wih + n * 64 + s * 32 + kg);
    } else {
      bf16x8 z;
#pragma unroll
      for (int j = 0; j < 8; ++j) z[j] = 0;
      if (kg == 0) z = ldfrag8(wih + n * 8);
      Wx[g][0] = z;
      Wx[g][1] = z;
    }
  }

  const float b_r = bih[cr] + bhh[cr];
  const float b_z = bih[64 + cr] + bhh[64 + cr];
  const float b_i = bih[128 + cr];
  const float b_h = bhh[128 + cr];
  float hold[4] = {0.f, 0.f, 0.f, 0.f};

  uint2 pf = make_uint2(0u, 0u);
  auto loadX = [&](int tt) {
    if (DIN == 64) {
      pf = *(const uint2*)(xin + ((size_t)tt * NB + b0 + (tid >> 4)) * 64 + (tid & 15) * 4);
    } else if (tid < 32) {
      pf = *(const uint2*)(xin + ((size_t)tt * NB + b0 + (tid >> 1)) * 8 + (tid & 1) * 4);
    }
  };
  auto commitX = [&](int buf) {
    if (DIN == 64) {
      *(uint2*)&xl[buf][tid >> 4][(tid & 15) * 4] = pf;
    } else if (tid < 32) {
      *(uint2*)&xl[buf][tid >> 1][(tid & 1) * 4] = pf;
    }
  };

  loadX(0);
  __syncthreads();   // orders zero-init before commit
  commitX(0);
  __syncthreads();   // orders commit before first reads

  int cur = 0;
  for (int t = 0; t < TP; ++t) {
    bf16x8 ax0 = *(const bf16x8*)&xl[cur][row][kg];
    bf16x8 ax1;
    if (DIN == 64) ax1 = *(const bf16x8*)&xl[cur][row][32 + kg];
    bf16x8 ah0 = *(const bf16x8*)&hl[cur][row][kg];
    bf16x8 ah1 = *(const bf16x8*)&hl[cur][row][32 + kg];
    if (t + 1 < TP) loadX(t + 1);

    f32x4 ar = {b_r, b_r, b_r, b_r};
    f32x4 az = {b_z, b_z, b_z, b_z};
    f32x4 ai = {b_i, b_i, b_i, b_i};
    f32x4 an = {b_h, b_h, b_h, b_h};

    ar = mfma16(ax0, Wx[0][0], ar);
    az = mfma16(ax0, Wx[1][0], az);
    ai = mfma16(ax0, Wx[2][0], ai);
    if (DIN == 64) {
      ar = mfma16(ax1, Wx[0][1], ar);
      az = mfma16(ax1, Wx[1][1], az);
      ai = mfma16(ax1, Wx[2][1], ai);
    }
    ar = mfma16(ah0, Wh[0][0], ar);
    ar = mfma16(ah1, Wh[0][1], ar);
    az = mfma16(ah0, Wh[1][0], az);
    az = mfma16(ah1, Wh[1][1], az);
    an = mfma16(ah0, Wh[2][0], an);
    an = mfma16(ah1, Wh[2][1], an);

    u16 hb[4];
#pragma unroll
    for (int r = 0; r < 4; ++r) {
      float rr = sigm(ar[r]);
      float zz = sigm(az[r]);
      float nn = tanh_(ai[r] + rr * an[r]);
      float hv = nn + zz * (hold[r] - nn);
      hold[r] = hv;
      hb[r] = f2bf(hv);
    }
    u16* dst = xout + ((size_t)t * NB + b0 + R0) * 64 + cr;
    dst[0] = hb[0]; dst[64] = hb[1]; dst[128] = hb[2]; dst[192] = hb[3];
    const int nxt = cur ^ 1;
#pragma unroll
    for (int r = 0; r < 4; ++r) hl[nxt][R0 + r][cr] = hb[r];
    if (t + 1 < TP) commitX(nxt);
    __syncthreads();
    cur = nxt;
  }
}

// -------- head: [28][B][64] bf16 -> sigmoid(B) --------
__global__ __launch_bounds__(256) void k_head(
    const u16* __restrict__ hseq, const float* __restrict__ ow,
    const float* __restrict__ ob, const float* __restrict__ o2w,
    const float* __restrict__ o2b, float* __restrict__ out)
{
  const int tid = threadIdx.x, lane = tid & 63, w = tid >> 6;
  const int b = blockIdx.x * 4 + w;
  const float wv = ow[lane];
  const float obv = ob[0];
  float acc = 0.f;
  for (int t = 0; t < TP; ++t) {
    float v = bf2f(hseq[((size_t)t * NB + b) * 64 + lane]) * wv;
#pragma unroll
    for (int m = 1; m <= 32; m <<= 1) v += __shfl_xor(v, m);
    acc += (v + obv) * o2w[t];
  }
  if (lane == 0) out[b] = sigm(acc + o2b[0]);
}

extern "C" void kernel_launch(void* const* d_in, const int* in_sizes, int n_in,
                              void* d_out, int out_size, void* d_ws, size_t ws_size,
                              hipStream_t stream)
{
  const float* poses = (const float*)d_in[0];
  const float* c1w = (const float*)d_in[1];
  const float* c1b = (const float*)d_in[2];
  const float* bn1g = (const float*)d_in[3];
  const float* bn1b = (const float*)d_in[4];
  const float* c2w = (const float*)d_in[5];
  const float* c2b = (const float*)d_in[6];
  const float* bn2g = (const float*)d_in[7];
  const float* bn2b = (const float*)d_in[8];
  const float* c3w = (const float*)d_in[9];
  const float* c3b = (const float*)d_in[10];
  const float* g0wih = (const float*)d_in[11];  // [192][8]
  const float* gwih = (const float*)d_in[12];   // [3][192][64]
  const float* gwhh = (const float*)d_in[13];   // [4][192][64]
  const float* gbih = (const float*)d_in[14];   // [4][192]
  const float* gbhh = (const float*)d_in[15];   // [4][192]
  const float* ow = (const float*)d_in[16];
  const float* ob = (const float*)d_in[17];
  const float* o2w = (const float*)d_in[18];
  const float* o2b = (const float*)d_in[19];

  float* ws = (float*)d_ws;
  float* y1 = ws;                         // 2,097,152 f32
  float* y2 = ws + 2097152;               //   983,040 f32
  u16* feat = (u16*)(ws + 3080192);       //   917,504 u16 (458,752 f32 slots)
  u16* bufA = (u16*)(ws + 3538944);       // 7,340,032 u16 (3,670,016 f32 slots)
  u16* bufB = (u16*)(ws + 7208960);       // 7,340,032 u16
  float* p1 = ws + 10878976;              //    32,768 f32
  float* p2 = ws + 10911744;              //     8,192 f32
  float* sc = ws + 10919936;              //        48 f32
  float* outv = (float*)d_out;

  k_conv1<<<dim3(1024), dim3(256), 0, stream>>>(poses, c1w, c1b, y1, p1);
  k_stats1<<<dim3(1), dim3(256), 0, stream>>>(p1, bn1g, bn1b, sc);
  k_conv2<<<dim3(512), dim3(256), 0, stream>>>(y1, sc, c2w, c2b, y2, p2);
  k_stats2<<<dim3(1), dim3(256), 0, stream>>>(p2, bn2g, bn2b, sc);
  k_conv3<<<dim3(512), dim3(256), 0, stream>>>(y2, sc, c3w, c3b, feat);
  k_gru<8><<<dim3(256), dim3(256), 0, stream>>>(feat, bufA, g0wih, gwhh + 0 * 12288, gbih + 0, gbhh + 0);
  k_gru<64><<<dim3(256), dim3(256), 0, stream>>>(bufA, bufB, gwih + 0 * 12288, gwhh + 1 * 12288, gbih + 192, gbhh + 192);
  k_gru<64><<<dim3(256), dim3(256), 0, stream>>>(bufB, bufA, gwih + 1 * 12288, gwhh + 2 * 12288, gbih + 384, gbhh + 384);
  k_gru<64><<<dim3(256), dim3(256), 0, stream>>>(bufA, bufB, gwih + 2 * 12288, gwhh + 3 * 12288, gbih + 576, gbhh + 576);
  k_head<<<dim3(1024), dim3(256), 0, stream>>>(bufB, ow, ob, o2w, o2b, outv);
}